// Round 7
// baseline (9298.277 us; speedup 1.0000x reference)
//
#include <hip/hip_runtime.h>
#include <math.h>

// Diffusion sampler: 49 sequential steps, rows independent.
// Round 7: fix LATENCY (VALUBusy 41%, VGPR 68 -> no loads in flight).
// - 8k-chunk ping-pong register prefetch in all GEMM loops (distance-1,
//   named buffers, unroll 2) -> 12-24 loads in flight.
// - Weights pre-transposed into ws (column-major per output col) -> each
//   lane streams contiguous memory, 1 address increment per chunk.
//   Fallback template<TR=false> with strided loads if ws too small.
// - LDS strides 296/264 (=8 mod 32) -> 2-way max bank aliasing (free).
// All f32. PRNG: JAX threefry2x32, partitionable mode.

#define DXY 288
#define HID 256
#define NTHR 512
#define XYP 296                 // xy_s stride; 296%32==8; pad doubles as overread target
#define HP  264                 // h_s stride;  264%32==8
#define OUT_Y_OFF 1048576
#define OUT_T_OFF 1179648
#define STEP_OFF 25600          // ws: [stepf,sstep] at STEP_OFF+2t (ct at t*512)
#define WS_W1 25728             // W1t[256 cols][288 k]
#define WS_W2 99584             // W2t[256][256]   (25728+73728+128)
#define WS_SW 165248            // SWt[288 cols][256 k] (99584+65536+128)
#define WS_NEED_BYTES ((size_t)(WS_SW + 73728 + 64) * 4)

typedef unsigned int u32;

__device__ __forceinline__ void tf2x32(u32 k0, u32 k1, u32 x0, u32 x1, u32& o0, u32& o1) {
  u32 ks2 = k0 ^ k1 ^ 0x1BD11BDAu;
#define TFR(r) { x0 += x1; x1 = (x1 << (r)) | (x1 >> (32 - (r))); x1 ^= x0; }
  x0 += k0; x1 += k1;
  TFR(13) TFR(15) TFR(26) TFR(6)
  x0 += k1;  x1 += ks2 + 1u;
  TFR(17) TFR(29) TFR(16) TFR(24)
  x0 += ks2; x1 += k0 + 2u;
  TFR(13) TFR(15) TFR(26) TFR(6)
  x0 += k0;  x1 += k1 + 3u;
  TFR(17) TFR(29) TFR(16) TFR(24)
  x0 += k1;  x1 += ks2 + 4u;
  TFR(13) TFR(15) TFR(26) TFR(6)
  x0 += ks2; x1 += k0 + 5u;
#undef TFR
  o0 = x0; o1 = x1;
}

__device__ __forceinline__ u32 pbits(u32 ka, u32 kb, u32 j) {
  u32 w0, w1;
  tf2x32(ka, kb, 0u, j, w0, w1);
  return w0 ^ w1;
}

__device__ __forceinline__ float u01f(u32 bits) {
  union { u32 i; float f; } v;
  v.i = (bits >> 9) | 0x3F800000u;
  return v.f - 1.0f;
}

// XLA f32 ErfInv (Giles polynomial)
__device__ __forceinline__ float erfinv32(float x) {
  float w = -log1pf(-x * x);
  float p;
  if (w < 5.0f) {
    w -= 2.5f;
    p = 2.81022636e-08f;
    p = fmaf(p, w, 3.43273939e-07f);
    p = fmaf(p, w, -3.5233877e-06f);
    p = fmaf(p, w, -4.39150654e-06f);
    p = fmaf(p, w, 0.00021858087f);
    p = fmaf(p, w, -0.00125372503f);
    p = fmaf(p, w, -0.00417768164f);
    p = fmaf(p, w, 0.246640727f);
    p = fmaf(p, w, 1.50140941f);
  } else {
    w = sqrtf(w) - 3.0f;
    p = -0.000200214257f;
    p = fmaf(p, w, 0.000100950558f);
    p = fmaf(p, w, 0.00134934322f);
    p = fmaf(p, w, -0.00367342844f);
    p = fmaf(p, w, 0.00573950773f);
    p = fmaf(p, w, -0.0076224613f);
    p = fmaf(p, w, 0.00943887047f);
    p = fmaf(p, w, 1.00167406f);
    p = fmaf(p, w, 2.83297682f);
  }
  return p * x;
}

__device__ __forceinline__ float nrmf(u32 bits) {
  float val = fmaf(u01f(bits), 2.0f, -0.99999994f);
  return 1.41421356f * erfinv32(val);
}
__device__ __forceinline__ float gumf(u32 bits) {
  float u = fmaxf(u01f(bits), 1.17549435e-38f);
  return -logf(-logf(u));
}
__device__ __forceinline__ float siluf(float x) {
  return x / (1.0f + expf(-x));
}

// ---- 8k-chunk register buffers ----
struct B8 { float4 a0, b0, a1, b1, a2, b2, a3, b3; };

template<bool TR, int LD>
__device__ __forceinline__ void loadB8(B8& B, const float* p, int kk) {
  if constexpr (TR) {
    // p = per-lane col base (4 contiguous col streams of length LD)
    B.a0 = *(const float4*)(p + 0 * LD + kk); B.b0 = *(const float4*)(p + 0 * LD + kk + 4);
    B.a1 = *(const float4*)(p + 1 * LD + kk); B.b1 = *(const float4*)(p + 1 * LD + kk + 4);
    B.a2 = *(const float4*)(p + 2 * LD + kk); B.b2 = *(const float4*)(p + 2 * LD + kk + 4);
    B.a3 = *(const float4*)(p + 3 * LD + kk); B.b3 = *(const float4*)(p + 3 * LD + kk + 4);
  } else {
    // p = w + cg; row-major, LD = row stride; a0..a3 = rows kk..kk+3, b0..b3 = kk+4..kk+7
    B.a0 = *(const float4*)(p + (kk + 0) * LD); B.a1 = *(const float4*)(p + (kk + 1) * LD);
    B.a2 = *(const float4*)(p + (kk + 2) * LD); B.a3 = *(const float4*)(p + (kk + 3) * LD);
    B.b0 = *(const float4*)(p + (kk + 4) * LD); B.b1 = *(const float4*)(p + (kk + 5) * LD);
    B.b2 = *(const float4*)(p + (kk + 6) * LD); B.b3 = *(const float4*)(p + (kk + 7) * LD);
  }
}

template<bool TR>
__device__ __forceinline__ void fma8x4(float acc[4], const float4 x0, const float4 x1, const B8& B) {
  if constexpr (TR) {
    acc[0]=fmaf(x0.x,B.a0.x,acc[0]); acc[0]=fmaf(x0.y,B.a0.y,acc[0]); acc[0]=fmaf(x0.z,B.a0.z,acc[0]); acc[0]=fmaf(x0.w,B.a0.w,acc[0]);
    acc[0]=fmaf(x1.x,B.b0.x,acc[0]); acc[0]=fmaf(x1.y,B.b0.y,acc[0]); acc[0]=fmaf(x1.z,B.b0.z,acc[0]); acc[0]=fmaf(x1.w,B.b0.w,acc[0]);
    acc[1]=fmaf(x0.x,B.a1.x,acc[1]); acc[1]=fmaf(x0.y,B.a1.y,acc[1]); acc[1]=fmaf(x0.z,B.a1.z,acc[1]); acc[1]=fmaf(x0.w,B.a1.w,acc[1]);
    acc[1]=fmaf(x1.x,B.b1.x,acc[1]); acc[1]=fmaf(x1.y,B.b1.y,acc[1]); acc[1]=fmaf(x1.z,B.b1.z,acc[1]); acc[1]=fmaf(x1.w,B.b1.w,acc[1]);
    acc[2]=fmaf(x0.x,B.a2.x,acc[2]); acc[2]=fmaf(x0.y,B.a2.y,acc[2]); acc[2]=fmaf(x0.z,B.a2.z,acc[2]); acc[2]=fmaf(x0.w,B.a2.w,acc[2]);
    acc[2]=fmaf(x1.x,B.b2.x,acc[2]); acc[2]=fmaf(x1.y,B.b2.y,acc[2]); acc[2]=fmaf(x1.z,B.b2.z,acc[2]); acc[2]=fmaf(x1.w,B.b2.w,acc[2]);
    acc[3]=fmaf(x0.x,B.a3.x,acc[3]); acc[3]=fmaf(x0.y,B.a3.y,acc[3]); acc[3]=fmaf(x0.z,B.a3.z,acc[3]); acc[3]=fmaf(x0.w,B.a3.w,acc[3]);
    acc[3]=fmaf(x1.x,B.b3.x,acc[3]); acc[3]=fmaf(x1.y,B.b3.y,acc[3]); acc[3]=fmaf(x1.z,B.b3.z,acc[3]); acc[3]=fmaf(x1.w,B.b3.w,acc[3]);
  } else {
    acc[0]=fmaf(x0.x,B.a0.x,acc[0]); acc[1]=fmaf(x0.x,B.a0.y,acc[1]); acc[2]=fmaf(x0.x,B.a0.z,acc[2]); acc[3]=fmaf(x0.x,B.a0.w,acc[3]);
    acc[0]=fmaf(x0.y,B.a1.x,acc[0]); acc[1]=fmaf(x0.y,B.a1.y,acc[1]); acc[2]=fmaf(x0.y,B.a1.z,acc[2]); acc[3]=fmaf(x0.y,B.a1.w,acc[3]);
    acc[0]=fmaf(x0.z,B.a2.x,acc[0]); acc[1]=fmaf(x0.z,B.a2.y,acc[1]); acc[2]=fmaf(x0.z,B.a2.z,acc[2]); acc[3]=fmaf(x0.z,B.a2.w,acc[3]);
    acc[0]=fmaf(x0.w,B.a3.x,acc[0]); acc[1]=fmaf(x0.w,B.a3.y,acc[1]); acc[2]=fmaf(x0.w,B.a3.z,acc[2]); acc[3]=fmaf(x0.w,B.a3.w,acc[3]);
    acc[0]=fmaf(x1.x,B.b0.x,acc[0]); acc[1]=fmaf(x1.x,B.b0.y,acc[1]); acc[2]=fmaf(x1.x,B.b0.z,acc[2]); acc[3]=fmaf(x1.x,B.b0.w,acc[3]);
    acc[0]=fmaf(x1.y,B.b1.x,acc[0]); acc[1]=fmaf(x1.y,B.b1.y,acc[1]); acc[2]=fmaf(x1.y,B.b1.z,acc[2]); acc[3]=fmaf(x1.y,B.b1.w,acc[3]);
    acc[0]=fmaf(x1.z,B.b2.x,acc[0]); acc[1]=fmaf(x1.z,B.b2.y,acc[1]); acc[2]=fmaf(x1.z,B.b2.z,acc[2]); acc[3]=fmaf(x1.z,B.b2.w,acc[3]);
    acc[0]=fmaf(x1.w,B.b3.x,acc[0]); acc[1]=fmaf(x1.w,B.b3.y,acc[1]); acc[2]=fmaf(x1.w,B.b3.z,acc[2]); acc[3]=fmaf(x1.w,B.b3.w,acc[3]);
  }
}

// 2-row x 4-col GEMM tile with ping-pong distance-1 prefetch.
// aA/aB rows have >=8 floats of legal pad past K (XYP/HP); TR weights padded in ws.
template<bool TR, int LD, int K>
__device__ __forceinline__ void gemm2(float accA[4], float accB[4],
                                      const float* bp, const float* aA, const float* aB) {
  B8 Bp, Bq;
  float4 xA0 = *(const float4*)(aA),     xA1 = *(const float4*)(aA + 4);
  float4 xB0 = *(const float4*)(aB),     xB1 = *(const float4*)(aB + 4);
  loadB8<TR, LD>(Bp, bp, 0);
  #pragma unroll 2
  for (int j = 0; j < K / 16; ++j) {
    const int k1 = j * 16 + 8;
    const int k2t = j * 16 + 16;
    const int k2 = (TR || k2t < K) ? k2t : 0;   // NT: clamp final dead prefetch in-bounds
    loadB8<TR, LD>(Bq, bp, k1);
    float4 yA0 = *(const float4*)(aA + k1), yA1 = *(const float4*)(aA + k1 + 4);
    float4 yB0 = *(const float4*)(aB + k1), yB1 = *(const float4*)(aB + k1 + 4);
    fma8x4<TR>(accA, xA0, xA1, Bp);
    fma8x4<TR>(accB, xB0, xB1, Bp);
    loadB8<TR, LD>(Bp, bp, k2);                 // last iter: dead (pad overread)
    xA0 = *(const float4*)(aA + k2); xA1 = *(const float4*)(aA + k2 + 4);
    xB0 = *(const float4*)(aB + k2); xB1 = *(const float4*)(aB + k2 + 4);
    fma8x4<TR>(accA, yA0, yA1, Bq);
    fma8x4<TR>(accB, yB0, yB1, Bq);
  }
}

// ---- precompute: Ct[t][k][c] and step scalars into ws ----
__global__ void precompute_ct(
    const float* __restrict__ t_embed,
    const float* __restrict__ tm_w1, const float* __restrict__ tm_b1,
    const float* __restrict__ tm_w2, const float* __restrict__ tm_b2,
    const float* __restrict__ tr_w1, const float* __restrict__ tr_b1,
    float* __restrict__ ws)
{
  const int t = blockIdx.x + 1;
  const int c = threadIdx.x;
  __shared__ float tmpre[HID];
  __shared__ float tmv[HID];
  const float tau = (float)t / 50.0f;

  tmpre[c] = siluf(fmaf(tau, tm_w1[c], tm_b1[c]));
  __syncthreads();
  {
    float acc = tm_b2[c];
    for (int i = 0; i < HID; i++)
      acc = fmaf(tmpre[i], tm_w2[i * HID + c], acc);
    tmv[c] = acc;
  }
  __syncthreads();
  float D = 0.f;
  for (int i = 0; i < HID; i++)
    D = fmaf(tmv[i], tr_w1[(544 + i) * HID + c], D);
  float ce0 = tr_b1[c], ce1 = tr_b1[c];
  for (int i = 0; i < HID; i++) {
    ce0 = fmaf(t_embed[i], tr_w1[(288 + i) * HID + c], ce0);
    ce1 = fmaf(t_embed[HID + i], tr_w1[(288 + i) * HID + c], ce1);
  }
  ws[t * 512 + c] = ce0 + D;
  ws[t * 512 + 256 + c] = ce1 + D;

  if (c == 0) {
    const double lt = 6.214608098422191;  // ln 500
    float sig_t = (float)(0.002 * exp(((double)t / 50.0) * lt));
    float sig_p = (float)(0.002 * exp(((double)(t - 1) / 50.0) * lt));
    float stepf = sig_t * sig_t - sig_p * sig_p;
    ws[STEP_OFF + 2 * t] = stepf;
    ws[STEP_OFF + 2 * t + 1] = sqrtf(stepf);
  }
}

// ---- transpose weights into ws (col-major per output column) ----
__global__ void transpose_w(const float* __restrict__ w1, const float* __restrict__ w2,
                            const float* __restrict__ sw, float* __restrict__ ws)
{
  int i = blockIdx.x * 256 + threadIdx.x;
  if (i < 73728) {                      // W1t[c][k], c<256, k<288
    int c = i / 288, k = i - c * 288;
    ws[WS_W1 + i] = w1[k * HID + c];
  } else if (i < 139264) {              // W2t[c][k], 256x256
    int j = i - 73728;
    int c = j >> 8, k = j & 255;
    ws[WS_W2 + j] = w2[(k << 8) + c];
  } else if (i < 212992) {              // SWt[c][k], c<288, k<256
    int m = i - 139264;
    int c = m >> 8, k = m & 255;
    ws[WS_SW + m] = sw[k * DXY + c];
  }
}

// ---- main sampler ----
template<bool TR>
__global__ __launch_bounds__(NTHR, 2) void sampler_k(
    const float* __restrict__ xy0, const int* __restrict__ t0,
    const float* __restrict__ tr_w1,
    const float* __restrict__ tr_w2, const float* __restrict__ tr_b2,
    const float* __restrict__ sh_w, const float* __restrict__ sh_b,
    const float* __restrict__ ch_w, const float* __restrict__ ch_b,
    const float* __restrict__ ws,
    float* __restrict__ out)
{
  __shared__ float xy_s[16][XYP];
  __shared__ float h1_s[16][HP];
  __shared__ float h2_s[16][HP];
  __shared__ float ct_s[2][HID];
  __shared__ int tcur_s[16];

  const int tid = threadIdx.x;
  const int lane = tid & 63;
  const int w = tid >> 6;                    // wave: col tile [32w, 32w+32)
  const int row0g = blockIdx.x * 16;

  const int r0 = lane >> 3;                  // rows r0, r0+8
  const int r1 = r0 + 8;
  const int cg = w * 32 + (lane & 7) * 4;    // 4 output cols
  const int rE = lane >> 2;                  // G3 extra: 16 rows x 4 cols/wave
  const int cE = 256 + w * 4 + (lane & 3);

  // per-lane weight base pointers
  const float* w1b = TR ? (ws + WS_W1 + cg * 288) : (tr_w1 + cg);
  const float* w2b = TR ? (ws + WS_W2 + cg * 256) : (tr_w2 + cg);
  const float* swb = TR ? (ws + WS_SW + cg * 256) : (sh_w + cg);
  const float* epb = TR ? (ws + WS_SW + cE * 256) : (sh_w + cE);

  // ---- prologue ----
  for (int idx = tid; idx < 16 * (DXY / 4); idx += NTHR) {
    int r = idx / (DXY / 4);
    int q = idx - r * (DXY / 4);
    *(float4*)&xy_s[r][q * 4] = *(const float4*)(xy0 + (row0g + r) * DXY + q * 4);
  }
  if (tid < 16) tcur_s[tid] = t0[row0g + tid];
  ((float*)ct_s)[tid] = ws[49 * 512 + tid];

  float chw0[4], chw1[4];
  #pragma unroll
  for (int j = 0; j < 4; j++) {
    chw0[j] = ch_w[(lane * 4 + j) * 2 + 0];
    chw1[j] = ch_w[(lane * 4 + j) * 2 + 1];
  }
  const float4 b2r = *(const float4*)(tr_b2 + cg);
  const float cb0 = ch_b[0], cb1 = ch_b[1];
  const float4 sbm = *(const float4*)(sh_b + cg);
  const float sbE = sh_b[cE];
  __syncthreads();

  #pragma unroll 1
  for (int t_idx = 49; t_idx >= 1; --t_idx) {
    const float stepf = ws[STEP_OFF + 2 * t_idx];
    const float sstep = ws[STEP_OFF + 2 * t_idx + 1];

    u32 f0, f1, k1a, k1b, k2a, k2b;
    tf2x32(0u, 42u, 0u, (u32)t_idx, f0, f1);
    tf2x32(f0, f1, 0u, 0u, k1a, k1b);
    tf2x32(f0, f1, 0u, 1u, k2a, k2b);

    // ---- G1: h1 = silu(xy @ W1[0:288] + Ct[t]) ----
    {
      const int tc0 = tcur_s[r0], tc1 = tcur_s[r1];
      float accA[4] = {0.f, 0.f, 0.f, 0.f};
      float accB[4] = {0.f, 0.f, 0.f, 0.f};
      gemm2<TR, TR ? 288 : HID, 288>(accA, accB, w1b, &xy_s[r0][0], &xy_s[r1][0]);
      const float4 ctA = *(const float4*)&ct_s[tc0][cg];
      const float4 ctB = *(const float4*)&ct_s[tc1][cg];
      float4 oA, oB;
      oA.x = siluf(accA[0] + ctA.x); oA.y = siluf(accA[1] + ctA.y);
      oA.z = siluf(accA[2] + ctA.z); oA.w = siluf(accA[3] + ctA.w);
      oB.x = siluf(accB[0] + ctB.x); oB.y = siluf(accB[1] + ctB.y);
      oB.z = siluf(accB[2] + ctB.z); oB.w = siluf(accB[3] + ctB.w);
      *(float4*)&h1_s[r0][cg] = oA;
      *(float4*)&h1_s[r1][cg] = oB;
    }
    __syncthreads();   // h1 ready

    // ---- G2: h2 = silu(h1 @ W2 + b2) ----
    {
      float accA[4] = {0.f, 0.f, 0.f, 0.f};
      float accB[4] = {0.f, 0.f, 0.f, 0.f};
      gemm2<TR, TR ? 256 : HID, 256>(accA, accB, w2b, &h1_s[r0][0], &h1_s[r1][0]);
      float4 oA, oB;
      oA.x = siluf(accA[0] + b2r.x); oA.y = siluf(accA[1] + b2r.y);
      oA.z = siluf(accA[2] + b2r.z); oA.w = siluf(accA[3] + b2r.w);
      oB.x = siluf(accB[0] + b2r.x); oB.y = siluf(accB[1] + b2r.y);
      oB.z = siluf(accB[2] + b2r.z); oB.w = siluf(accB[3] + b2r.w);
      *(float4*)&h2_s[r0][cg] = oA;
      *(float4*)&h2_s[r1][cg] = oB;
    }
    __syncthreads();   // h2 ready

    // ---- logits + categorical for rows {2w, 2w+1} ----
    {
      float4 hL0 = *(const float4*)&h2_s[2 * w][lane * 4];
      float4 hL1 = *(const float4*)&h2_s[2 * w + 1][lane * 4];
      float pA0 = hL0.x * chw0[0] + hL0.y * chw0[1] + hL0.z * chw0[2] + hL0.w * chw0[3];
      float pA1 = hL0.x * chw1[0] + hL0.y * chw1[1] + hL0.z * chw1[2] + hL0.w * chw1[3];
      float pB0 = hL1.x * chw0[0] + hL1.y * chw0[1] + hL1.z * chw0[2] + hL1.w * chw0[3];
      float pB1 = hL1.x * chw1[0] + hL1.y * chw1[1] + hL1.z * chw1[2] + hL1.w * chw1[3];
      #pragma unroll
      for (int off = 32; off > 0; off >>= 1) {
        pA0 += __shfl_xor(pA0, off);
        pA1 += __shfl_xor(pA1, off);
        pB0 += __shfl_xor(pB0, off);
        pB1 += __shfl_xor(pB1, off);
      }
      u32 grow = (u32)(row0g + 2 * w + ((lane >> 1) & 1));
      float g = gumf(pbits(k2a, k2b, grow * 2u + (u32)(lane & 1)));
      float g0 = __shfl(g, 0), g1 = __shfl(g, 1);
      float g2 = __shfl(g, 2), g3 = __shfl(g, 3);
      if (lane == 0) {
        tcur_s[2 * w]     = (pA1 + cb1 + g1 > pA0 + cb0 + g0) ? 1 : 0;
        tcur_s[2 * w + 1] = (pB1 + cb1 + g3 > pB0 + cb0 + g2) ? 1 : 0;
      }
    }

    // ---- G3 main: score cols 0..255; xy += step*score + sqrt(step)*noise ----
    {
      float accA[4] = {0.f, 0.f, 0.f, 0.f};
      float accB[4] = {0.f, 0.f, 0.f, 0.f};
      gemm2<TR, TR ? 256 : DXY, 256>(accA, accB, swb, &h2_s[r0][0], &h2_s[r1][0]);
      const u32 jA = (u32)(row0g + r0) * 288u + (u32)cg;
      const u32 jB = (u32)(row0g + r1) * 288u + (u32)cg;
      float4 xA = *(const float4*)&xy_s[r0][cg];
      float4 xB = *(const float4*)&xy_s[r1][cg];
      xA.x = fmaf(sstep, nrmf(pbits(k1a, k1b, jA + 0u)), fmaf(stepf, accA[0] + sbm.x, xA.x));
      xA.y = fmaf(sstep, nrmf(pbits(k1a, k1b, jA + 1u)), fmaf(stepf, accA[1] + sbm.y, xA.y));
      xA.z = fmaf(sstep, nrmf(pbits(k1a, k1b, jA + 2u)), fmaf(stepf, accA[2] + sbm.z, xA.z));
      xA.w = fmaf(sstep, nrmf(pbits(k1a, k1b, jA + 3u)), fmaf(stepf, accA[3] + sbm.w, xA.w));
      xB.x = fmaf(sstep, nrmf(pbits(k1a, k1b, jB + 0u)), fmaf(stepf, accB[0] + sbm.x, xB.x));
      xB.y = fmaf(sstep, nrmf(pbits(k1a, k1b, jB + 1u)), fmaf(stepf, accB[1] + sbm.y, xB.y));
      xB.z = fmaf(sstep, nrmf(pbits(k1a, k1b, jB + 2u)), fmaf(stepf, accB[2] + sbm.z, xB.z));
      xB.w = fmaf(sstep, nrmf(pbits(k1a, k1b, jB + 3u)), fmaf(stepf, accB[3] + sbm.w, xB.w));
      *(float4*)&xy_s[r0][cg] = xA;
      *(float4*)&xy_s[r1][cg] = xB;
    }

    // ---- G3 extra: cols 256..287 (wave w: 4 cols, 16 rows) ----
    {
      float sE0 = 0.f, sE1 = 0.f;
      #pragma unroll 4
      for (int k = 0; k < 256; k += 8) {
        float4 h0  = *(const float4*)&h2_s[rE][k];
        float4 h1v = *(const float4*)&h2_s[rE][k + 4];
        if constexpr (TR) {
          float4 wa = *(const float4*)(epb + k);
          float4 wb = *(const float4*)(epb + k + 4);
          sE0 = fmaf(h0.w, wa.w, fmaf(h0.z, wa.z, fmaf(h0.y, wa.y, fmaf(h0.x, wa.x, sE0))));
          sE1 = fmaf(h1v.w, wb.w, fmaf(h1v.z, wb.z, fmaf(h1v.y, wb.y, fmaf(h1v.x, wb.x, sE1))));
        } else {
          const float* bp2 = epb + k * DXY;
          sE0 = fmaf(h0.w, bp2[3 * DXY], fmaf(h0.z, bp2[2 * DXY], fmaf(h0.y, bp2[DXY], fmaf(h0.x, bp2[0], sE0))));
          sE1 = fmaf(h1v.w, bp2[7 * DXY], fmaf(h1v.z, bp2[6 * DXY], fmaf(h1v.y, bp2[5 * DXY], fmaf(h1v.x, bp2[4 * DXY], sE1))));
        }
      }
      float sE = sE0 + sE1;
      u32 jE = (u32)(row0g + rE) * 288u + (u32)cE;
      float nE = nrmf(pbits(k1a, k1b, jE));
      xy_s[rE][cE] = fmaf(sstep, nE, fmaf(stepf, sE + sbE, xy_s[rE][cE]));
    }

    // ---- stage Ct for next step ----
    if (t_idx > 1) ((float*)ct_s)[tid] = ws[(t_idx - 1) * 512 + tid];
    __syncthreads();   // xy/tcur/ct ready for next G1
  }

  // ---- final store ----
  for (int idx = tid; idx < 16 * 64; idx += NTHR) {
    int r = idx >> 6;
    int c4 = (idx & 63) * 4;
    *(float4*)(out + (row0g + r) * 256 + c4) = *(const float4*)&xy_s[r][c4];
  }
  for (int idx = tid; idx < 16 * 8; idx += NTHR) {
    int r = idx >> 3;
    int c4 = (idx & 7) * 4;
    *(float4*)(out + OUT_Y_OFF + (row0g + r) * 32 + c4) = *(const float4*)&xy_s[r][256 + c4];
  }
  if (tid < 16) out[OUT_T_OFF + row0g + tid] = (float)tcur_s[tid];
}

extern "C" void kernel_launch(void* const* d_in, const int* in_sizes, int n_in,
                              void* d_out, int out_size, void* d_ws, size_t ws_size,
                              hipStream_t stream) {
  (void)in_sizes; (void)n_in; (void)out_size;
  const float* xy0     = (const float*)d_in[0];
  const int*   t0      = (const int*)d_in[1];
  const float* t_embed = (const float*)d_in[2];
  const float* tm_w1   = (const float*)d_in[3];
  const float* tm_b1   = (const float*)d_in[4];
  const float* tm_w2   = (const float*)d_in[5];
  const float* tm_b2   = (const float*)d_in[6];
  const float* tr_w1   = (const float*)d_in[7];
  const float* tr_b1   = (const float*)d_in[8];
  const float* tr_w2   = (const float*)d_in[9];
  const float* tr_b2   = (const float*)d_in[10];
  const float* sh_w    = (const float*)d_in[11];
  const float* sh_b    = (const float*)d_in[12];
  const float* ch_w    = (const float*)d_in[13];
  const float* ch_b    = (const float*)d_in[14];
  float* ws  = (float*)d_ws;
  float* out = (float*)d_out;

  precompute_ct<<<49, 256, 0, stream>>>(t_embed, tm_w1, tm_b1, tm_w2, tm_b2,
                                        tr_w1, tr_b1, ws);
  if (ws_size >= WS_NEED_BYTES) {
    transpose_w<<<832, 256, 0, stream>>>(tr_w1, tr_w2, sh_w, ws);
    sampler_k<true><<<256, NTHR, 0, stream>>>(xy0, t0, tr_w1, tr_w2, tr_b2,
                                              sh_w, sh_b, ch_w, ch_b, ws, out);
  } else {
    sampler_k<false><<<256, NTHR, 0, stream>>>(xy0, t0, tr_w1, tr_w2, tr_b2,
                                               sh_w, sh_b, ch_w, ch_b, ws, out);
  }
}

// Round 8
// 4754.560 us; speedup vs baseline: 1.9557x; 1.9557x over previous
//
#include <hip/hip_runtime.h>
#include <math.h>

// Diffusion sampler: 49 sequential steps, rows independent.
// Round 8: latency fix via occupancy + explicit prefetch.
// 256 blocks x 1024 threads (4 waves/SIMD). 16 rows/block; wave w owns cols
// [16w,16w+16); each lane: 2 rows x 2 cols (float2 weight loads, coalesced).
// Distance-1 ping-pong register prefetch (named buffers). Weights stream once
// per CU per step (row-major layout kept: 2 cache lines per load instr).
// All f32. PRNG: JAX threefry2x32, partitionable mode.

#define DXY 288
#define HID 256
#define NTHR 1024
#define XYP 296                 // xy_s stride (%32==8 -> 2-way max on GEMM reads)
#define HP  264                 // h_s stride
#define OUT_Y_OFF 1048576
#define OUT_T_OFF 1179648
#define STEP_OFF 25600          // ws: ct at t*512; [stepf,sstep] at STEP_OFF+2t

typedef unsigned int u32;

__device__ __forceinline__ void tf2x32(u32 k0, u32 k1, u32 x0, u32 x1, u32& o0, u32& o1) {
  u32 ks2 = k0 ^ k1 ^ 0x1BD11BDAu;
#define TFR(r) { x0 += x1; x1 = (x1 << (r)) | (x1 >> (32 - (r))); x1 ^= x0; }
  x0 += k0; x1 += k1;
  TFR(13) TFR(15) TFR(26) TFR(6)
  x0 += k1;  x1 += ks2 + 1u;
  TFR(17) TFR(29) TFR(16) TFR(24)
  x0 += ks2; x1 += k0 + 2u;
  TFR(13) TFR(15) TFR(26) TFR(6)
  x0 += k0;  x1 += k1 + 3u;
  TFR(17) TFR(29) TFR(16) TFR(24)
  x0 += k1;  x1 += ks2 + 4u;
  TFR(13) TFR(15) TFR(26) TFR(6)
  x0 += ks2; x1 += k0 + 5u;
#undef TFR
  o0 = x0; o1 = x1;
}

__device__ __forceinline__ u32 pbits(u32 ka, u32 kb, u32 j) {
  u32 w0, w1;
  tf2x32(ka, kb, 0u, j, w0, w1);
  return w0 ^ w1;
}

__device__ __forceinline__ float u01f(u32 bits) {
  union { u32 i; float f; } v;
  v.i = (bits >> 9) | 0x3F800000u;
  return v.f - 1.0f;
}

// XLA f32 ErfInv (Giles polynomial)
__device__ __forceinline__ float erfinv32(float x) {
  float w = -log1pf(-x * x);
  float p;
  if (w < 5.0f) {
    w -= 2.5f;
    p = 2.81022636e-08f;
    p = fmaf(p, w, 3.43273939e-07f);
    p = fmaf(p, w, -3.5233877e-06f);
    p = fmaf(p, w, -4.39150654e-06f);
    p = fmaf(p, w, 0.00021858087f);
    p = fmaf(p, w, -0.00125372503f);
    p = fmaf(p, w, -0.00417768164f);
    p = fmaf(p, w, 0.246640727f);
    p = fmaf(p, w, 1.50140941f);
  } else {
    w = sqrtf(w) - 3.0f;
    p = -0.000200214257f;
    p = fmaf(p, w, 0.000100950558f);
    p = fmaf(p, w, 0.00134934322f);
    p = fmaf(p, w, -0.00367342844f);
    p = fmaf(p, w, 0.00573950773f);
    p = fmaf(p, w, -0.0076224613f);
    p = fmaf(p, w, 0.00943887047f);
    p = fmaf(p, w, 1.00167406f);
    p = fmaf(p, w, 2.83297682f);
  }
  return p * x;
}

__device__ __forceinline__ float nrmf(u32 bits) {
  float val = fmaf(u01f(bits), 2.0f, -0.99999994f);
  return 1.41421356f * erfinv32(val);
}
__device__ __forceinline__ float gumf(u32 bits) {
  float u = fmaxf(u01f(bits), 1.17549435e-38f);
  return -logf(-logf(u));
}
__device__ __forceinline__ float siluf(float x) {
  return x / (1.0f + expf(-x));
}

// ---- 8k weight chunk: 8 float2 (2 cols), row-major (coalesced) ----
struct Bf2 { float2 r0, r1, r2, r3, r4, r5, r6, r7; };

template<int LD>
__device__ __forceinline__ void loadBf2(Bf2& B, const float* p, int kk) {
  const float* q = p + kk * LD;
  B.r0 = *(const float2*)(q);
  B.r1 = *(const float2*)(q + LD);
  B.r2 = *(const float2*)(q + 2 * LD);
  B.r3 = *(const float2*)(q + 3 * LD);
  B.r4 = *(const float2*)(q + 4 * LD);
  B.r5 = *(const float2*)(q + 5 * LD);
  B.r6 = *(const float2*)(q + 6 * LD);
  B.r7 = *(const float2*)(q + 7 * LD);
}

__device__ __forceinline__ void fmaBf2(float acc[4], const float4 a0, const float4 a1,
                                       const float4 b0, const float4 b1, const Bf2& B) {
  acc[0]=fmaf(a0.x,B.r0.x,acc[0]); acc[1]=fmaf(a0.x,B.r0.y,acc[1]);
  acc[2]=fmaf(b0.x,B.r0.x,acc[2]); acc[3]=fmaf(b0.x,B.r0.y,acc[3]);
  acc[0]=fmaf(a0.y,B.r1.x,acc[0]); acc[1]=fmaf(a0.y,B.r1.y,acc[1]);
  acc[2]=fmaf(b0.y,B.r1.x,acc[2]); acc[3]=fmaf(b0.y,B.r1.y,acc[3]);
  acc[0]=fmaf(a0.z,B.r2.x,acc[0]); acc[1]=fmaf(a0.z,B.r2.y,acc[1]);
  acc[2]=fmaf(b0.z,B.r2.x,acc[2]); acc[3]=fmaf(b0.z,B.r2.y,acc[3]);
  acc[0]=fmaf(a0.w,B.r3.x,acc[0]); acc[1]=fmaf(a0.w,B.r3.y,acc[1]);
  acc[2]=fmaf(b0.w,B.r3.x,acc[2]); acc[3]=fmaf(b0.w,B.r3.y,acc[3]);
  acc[0]=fmaf(a1.x,B.r4.x,acc[0]); acc[1]=fmaf(a1.x,B.r4.y,acc[1]);
  acc[2]=fmaf(b1.x,B.r4.x,acc[2]); acc[3]=fmaf(b1.x,B.r4.y,acc[3]);
  acc[0]=fmaf(a1.y,B.r5.x,acc[0]); acc[1]=fmaf(a1.y,B.r5.y,acc[1]);
  acc[2]=fmaf(b1.y,B.r5.x,acc[2]); acc[3]=fmaf(b1.y,B.r5.y,acc[3]);
  acc[0]=fmaf(a1.z,B.r6.x,acc[0]); acc[1]=fmaf(a1.z,B.r6.y,acc[1]);
  acc[2]=fmaf(b1.z,B.r6.x,acc[2]); acc[3]=fmaf(b1.z,B.r6.y,acc[3]);
  acc[0]=fmaf(a1.w,B.r7.x,acc[0]); acc[1]=fmaf(a1.w,B.r7.y,acc[1]);
  acc[2]=fmaf(b1.w,B.r7.x,acc[2]); acc[3]=fmaf(b1.w,B.r7.y,acc[3]);
}

// 2-row x 2-col GEMM with distance-1 ping-pong prefetch. K%16==0.
template<int LD, int K>
__device__ __forceinline__ void gemmf2(float acc[4], const float* wp,
                                       const float* aA, const float* aB) {
  constexpr int n = K / 8;   // even
  Bf2 Bp, Bq;
  float4 xA0, xA1, xB0, xB1, yA0, yA1, yB0, yB1;
  loadBf2<LD>(Bp, wp, 0);
  xA0 = *(const float4*)(aA);     xA1 = *(const float4*)(aA + 4);
  xB0 = *(const float4*)(aB);     xB1 = *(const float4*)(aB + 4);
  #pragma unroll 2
  for (int j = 0; j < n; j += 2) {
    const int k1 = (j + 1) * 8;
    loadBf2<LD>(Bq, wp, k1);
    yA0 = *(const float4*)(aA + k1); yA1 = *(const float4*)(aA + k1 + 4);
    yB0 = *(const float4*)(aB + k1); yB1 = *(const float4*)(aB + k1 + 4);
    fmaBf2(acc, xA0, xA1, xB0, xB1, Bp);
    const int k2 = (j + 2 < n) ? (j + 2) * 8 : 0;   // last: dead in-bounds prefetch
    loadBf2<LD>(Bp, wp, k2);
    xA0 = *(const float4*)(aA + k2); xA1 = *(const float4*)(aA + k2 + 4);
    xB0 = *(const float4*)(aB + k2); xB1 = *(const float4*)(aB + k2 + 4);
    fmaBf2(acc, yA0, yA1, yB0, yB1, Bq);
  }
}

// ---- precompute: Ct[t][k][c] and step scalars into ws ----
__global__ void precompute_ct(
    const float* __restrict__ t_embed,
    const float* __restrict__ tm_w1, const float* __restrict__ tm_b1,
    const float* __restrict__ tm_w2, const float* __restrict__ tm_b2,
    const float* __restrict__ tr_w1, const float* __restrict__ tr_b1,
    float* __restrict__ ws)
{
  const int t = blockIdx.x + 1;
  const int c = threadIdx.x;
  __shared__ float tmpre[HID];
  __shared__ float tmv[HID];
  const float tau = (float)t / 50.0f;

  tmpre[c] = siluf(fmaf(tau, tm_w1[c], tm_b1[c]));
  __syncthreads();
  {
    float acc = tm_b2[c];
    for (int i = 0; i < HID; i++)
      acc = fmaf(tmpre[i], tm_w2[i * HID + c], acc);
    tmv[c] = acc;
  }
  __syncthreads();
  float D = 0.f;
  for (int i = 0; i < HID; i++)
    D = fmaf(tmv[i], tr_w1[(544 + i) * HID + c], D);
  float ce0 = tr_b1[c], ce1 = tr_b1[c];
  for (int i = 0; i < HID; i++) {
    ce0 = fmaf(t_embed[i], tr_w1[(288 + i) * HID + c], ce0);
    ce1 = fmaf(t_embed[HID + i], tr_w1[(288 + i) * HID + c], ce1);
  }
  ws[t * 512 + c] = ce0 + D;
  ws[t * 512 + 256 + c] = ce1 + D;

  if (c == 0) {
    const double lt = 6.214608098422191;  // ln 500
    float sig_t = (float)(0.002 * exp(((double)t / 50.0) * lt));
    float sig_p = (float)(0.002 * exp(((double)(t - 1) / 50.0) * lt));
    float stepf = sig_t * sig_t - sig_p * sig_p;
    ws[STEP_OFF + 2 * t] = stepf;
    ws[STEP_OFF + 2 * t + 1] = sqrtf(stepf);
  }
}

// ---- main sampler ----
__global__ __launch_bounds__(NTHR, 4) void sampler_k(
    const float* __restrict__ xy0, const int* __restrict__ t0,
    const float* __restrict__ tr_w1,
    const float* __restrict__ tr_w2, const float* __restrict__ tr_b2,
    const float* __restrict__ sh_w, const float* __restrict__ sh_b,
    const float* __restrict__ ch_w, const float* __restrict__ ch_b,
    const float* __restrict__ ws,
    float* __restrict__ out)
{
  __shared__ float xy_s[16][XYP];
  __shared__ float h1_s[16][HP];
  __shared__ float h2_s[16][HP];
  __shared__ float ct_s[2][HID];
  __shared__ int tcur_s[16];

  const int tid = threadIdx.x;
  const int lane = tid & 63;
  const int w = tid >> 6;                      // 16 waves; cols [16w, 16w+16)
  const int row0g = blockIdx.x * 16;

  const int r0 = lane >> 3;                    // rows r0, r0+8
  const int r1 = r0 + 8;
  const int cg = w * 16 + (lane & 7) * 2;      // 2 output cols
  const int rE = lane >> 2;                    // G3 extra (waves 0-7)
  const int cE = 256 + (w & 7) * 4 + (lane & 3);

  const float* w1b = tr_w1 + cg;
  const float* w2b = tr_w2 + cg;
  const float* swb = sh_w + cg;
  const float* epb = sh_w + cE;

  // ---- prologue ----
  for (int idx = tid; idx < 16 * (DXY / 4); idx += NTHR) {
    int r = idx / (DXY / 4);
    int q = idx - r * (DXY / 4);
    *(float4*)&xy_s[r][q * 4] = *(const float4*)(xy0 + (row0g + r) * DXY + q * 4);
  }
  if (tid < 16) tcur_s[tid] = t0[row0g + tid];
  if (tid < 512) ((float*)ct_s)[tid] = ws[49 * 512 + tid];

  float chw0[4], chw1[4];                      // logits: cols lane*4..+3
  #pragma unroll
  for (int j = 0; j < 4; j++) {
    chw0[j] = ch_w[(lane * 4 + j) * 2 + 0];
    chw1[j] = ch_w[(lane * 4 + j) * 2 + 1];
  }
  const float2 b2r = *(const float2*)(tr_b2 + cg);
  const float cb0 = ch_b[0], cb1 = ch_b[1];
  const float2 sbm = *(const float2*)(sh_b + cg);
  const float sbE = sh_b[cE];
  __syncthreads();

  #pragma unroll 1
  for (int t_idx = 49; t_idx >= 1; --t_idx) {
    const float stepf = ws[STEP_OFF + 2 * t_idx];
    const float sstep = ws[STEP_OFF + 2 * t_idx + 1];

    u32 f0, f1, k1a, k1b, k2a, k2b;
    tf2x32(0u, 42u, 0u, (u32)t_idx, f0, f1);
    tf2x32(f0, f1, 0u, 0u, k1a, k1b);
    tf2x32(f0, f1, 0u, 1u, k2a, k2b);

    // ---- G1: h1 = silu(xy @ W1[0:288] + Ct[t]) ----
    {
      const int tc0 = tcur_s[r0], tc1 = tcur_s[r1];
      float acc[4] = {0.f, 0.f, 0.f, 0.f};
      gemmf2<HID, 288>(acc, w1b, &xy_s[r0][0], &xy_s[r1][0]);
      const float2 ctA = *(const float2*)&ct_s[tc0][cg];
      const float2 ctB = *(const float2*)&ct_s[tc1][cg];
      float2 oA, oB;
      oA.x = siluf(acc[0] + ctA.x); oA.y = siluf(acc[1] + ctA.y);
      oB.x = siluf(acc[2] + ctB.x); oB.y = siluf(acc[3] + ctB.y);
      *(float2*)&h1_s[r0][cg] = oA;
      *(float2*)&h1_s[r1][cg] = oB;
    }
    __syncthreads();   // h1 ready

    // ---- G2: h2 = silu(h1 @ W2 + b2) ----
    {
      float acc[4] = {0.f, 0.f, 0.f, 0.f};
      gemmf2<HID, 256>(acc, w2b, &h1_s[r0][0], &h1_s[r1][0]);
      float2 oA, oB;
      oA.x = siluf(acc[0] + b2r.x); oA.y = siluf(acc[1] + b2r.y);
      oB.x = siluf(acc[2] + b2r.x); oB.y = siluf(acc[3] + b2r.y);
      *(float2*)&h2_s[r0][cg] = oA;
      *(float2*)&h2_s[r1][cg] = oB;
    }
    __syncthreads();   // h2 ready

    // ---- logits + categorical: wave w -> row w ----
    {
      float4 hL = *(const float4*)&h2_s[w][lane * 4];
      float p0 = hL.x * chw0[0] + hL.y * chw0[1] + hL.z * chw0[2] + hL.w * chw0[3];
      float p1 = hL.x * chw1[0] + hL.y * chw1[1] + hL.z * chw1[2] + hL.w * chw1[3];
      #pragma unroll
      for (int off = 32; off > 0; off >>= 1) {
        p0 += __shfl_xor(p0, off);
        p1 += __shfl_xor(p1, off);
      }
      float g = gumf(pbits(k2a, k2b, (u32)(row0g + w) * 2u + (u32)(lane & 1)));
      float g0 = __shfl(g, 0), g1 = __shfl(g, 1);
      if (lane == 0)
        tcur_s[w] = (p1 + cb1 + g1 > p0 + cb0 + g0) ? 1 : 0;
    }

    // ---- G3 main: score cols 0..255; xy += step*score + sqrt(step)*noise ----
    {
      float acc[4] = {0.f, 0.f, 0.f, 0.f};
      gemmf2<DXY, 256>(acc, swb, &h2_s[r0][0], &h2_s[r1][0]);
      const u32 jA = (u32)(row0g + r0) * 288u + (u32)cg;
      const u32 jB = (u32)(row0g + r1) * 288u + (u32)cg;
      float2 xA = *(const float2*)&xy_s[r0][cg];
      float2 xB = *(const float2*)&xy_s[r1][cg];
      xA.x = fmaf(sstep, nrmf(pbits(k1a, k1b, jA + 0u)), fmaf(stepf, acc[0] + sbm.x, xA.x));
      xA.y = fmaf(sstep, nrmf(pbits(k1a, k1b, jA + 1u)), fmaf(stepf, acc[1] + sbm.y, xA.y));
      xB.x = fmaf(sstep, nrmf(pbits(k1a, k1b, jB + 0u)), fmaf(stepf, acc[2] + sbm.x, xB.x));
      xB.y = fmaf(sstep, nrmf(pbits(k1a, k1b, jB + 1u)), fmaf(stepf, acc[3] + sbm.y, xB.y));
      *(float2*)&xy_s[r0][cg] = xA;
      *(float2*)&xy_s[r1][cg] = xB;
    }

    // ---- G3 extra: cols 256..287 (waves 0-7: 4 cols x 16 rows, 1/lane) ----
    if (w < 8) {
      float sE0 = 0.f, sE1 = 0.f;
      #pragma unroll 4
      for (int k = 0; k < 256; k += 8) {
        float4 h0  = *(const float4*)&h2_s[rE][k];
        float4 h1v = *(const float4*)&h2_s[rE][k + 4];
        const float* bp2 = epb + k * DXY;
        sE0 = fmaf(h0.w, bp2[3 * DXY], fmaf(h0.z, bp2[2 * DXY], fmaf(h0.y, bp2[DXY], fmaf(h0.x, bp2[0], sE0))));
        sE1 = fmaf(h1v.w, bp2[7 * DXY], fmaf(h1v.z, bp2[6 * DXY], fmaf(h1v.y, bp2[5 * DXY], fmaf(h1v.x, bp2[4 * DXY], sE1))));
      }
      float sE = sE0 + sE1;
      u32 jE = (u32)(row0g + rE) * 288u + (u32)cE;
      float nE = nrmf(pbits(k1a, k1b, jE));
      xy_s[rE][cE] = fmaf(sstep, nE, fmaf(stepf, sE + sbE, xy_s[rE][cE]));
    }

    // ---- stage Ct for next step ----
    if (t_idx > 1 && tid < 512) ((float*)ct_s)[tid] = ws[(t_idx - 1) * 512 + tid];
    __syncthreads();   // xy/tcur/ct ready for next G1
  }

  // ---- final store: x (4096x256), y (4096x32), t (4096) ----
  {
    int r = tid >> 6;
    int c4 = (tid & 63) * 4;
    *(float4*)(out + (row0g + r) * 256 + c4) = *(const float4*)&xy_s[r][c4];
  }
  if (tid < 16 * 8) {
    int r = tid >> 3;
    int c4 = (tid & 7) * 4;
    *(float4*)(out + OUT_Y_OFF + (row0g + r) * 32 + c4) = *(const float4*)&xy_s[r][256 + c4];
  }
  if (tid < 16) out[OUT_T_OFF + row0g + tid] = (float)tcur_s[tid];
}

extern "C" void kernel_launch(void* const* d_in, const int* in_sizes, int n_in,
                              void* d_out, int out_size, void* d_ws, size_t ws_size,
                              hipStream_t stream) {
  (void)in_sizes; (void)n_in; (void)ws_size; (void)out_size;
  const float* xy0     = (const float*)d_in[0];
  const int*   t0      = (const int*)d_in[1];
  const float* t_embed = (const float*)d_in[2];
  const float* tm_w1   = (const float*)d_in[3];
  const float* tm_b1   = (const float*)d_in[4];
  const float* tm_w2   = (const float*)d_in[5];
  const float* tm_b2   = (const float*)d_in[6];
  const float* tr_w1   = (const float*)d_in[7];
  const float* tr_b1   = (const float*)d_in[8];
  const float* tr_w2   = (const float*)d_in[9];
  const float* tr_b2   = (const float*)d_in[10];
  const float* sh_w    = (const float*)d_in[11];
  const float* sh_b    = (const float*)d_in[12];
  const float* ch_w    = (const float*)d_in[13];
  const float* ch_b    = (const float*)d_in[14];
  float* ws  = (float*)d_ws;
  float* out = (float*)d_out;

  precompute_ct<<<49, 256, 0, stream>>>(t_embed, tm_w1, tm_b1, tm_w2, tm_b2,
                                        tr_w1, tr_b1, ws);
  sampler_k<<<256, NTHR, 0, stream>>>(xy0, t0, tr_w1, tr_w2, tr_b2,
                                      sh_w, sh_b, ch_w, ch_b, ws, out);
}

// Round 9
// 4750.109 us; speedup vs baseline: 1.9575x; 1.0009x over previous
//
#include <hip/hip_runtime.h>
#include <math.h>

// Diffusion sampler: 49 sequential steps, rows independent.
// Round 9: R8 structure, launch_bounds fixed to (1024, 1).
// Evidence: hipcc 2nd launch_bounds arg == min BLOCKS/CU (measured VGPR ladder
// R3/R4/R5/R8). (1024,4) clamped to 32 waves/CU -> 64-VGPR cap -> prefetch
// spilled to scratch (WRITE_SIZE 23MB). (1024,1) -> 16 waves/CU, 128-VGPR cap.
// 256 blocks x 1024 threads; 16 rows/block; wave w owns cols [16w,16w+16);
// lane: 2 rows x 2 cols; distance-1 ping-pong register prefetch; weights
// stream once per CU per step. All f32. PRNG: JAX threefry2x32 partitionable.

#define DXY 288
#define HID 256
#define NTHR 1024
#define XYP 296                 // xy_s stride (%32==8 -> 2-way max on GEMM reads)
#define HP  264                 // h_s stride
#define OUT_Y_OFF 1048576
#define OUT_T_OFF 1179648
#define STEP_OFF 25600          // ws: ct at t*512; [stepf,sstep] at STEP_OFF+2t

typedef unsigned int u32;

__device__ __forceinline__ void tf2x32(u32 k0, u32 k1, u32 x0, u32 x1, u32& o0, u32& o1) {
  u32 ks2 = k0 ^ k1 ^ 0x1BD11BDAu;
#define TFR(r) { x0 += x1; x1 = (x1 << (r)) | (x1 >> (32 - (r))); x1 ^= x0; }
  x0 += k0; x1 += k1;
  TFR(13) TFR(15) TFR(26) TFR(6)
  x0 += k1;  x1 += ks2 + 1u;
  TFR(17) TFR(29) TFR(16) TFR(24)
  x0 += ks2; x1 += k0 + 2u;
  TFR(13) TFR(15) TFR(26) TFR(6)
  x0 += k0;  x1 += k1 + 3u;
  TFR(17) TFR(29) TFR(16) TFR(24)
  x0 += k1;  x1 += ks2 + 4u;
  TFR(13) TFR(15) TFR(26) TFR(6)
  x0 += ks2; x1 += k0 + 5u;
#undef TFR
  o0 = x0; o1 = x1;
}

__device__ __forceinline__ u32 pbits(u32 ka, u32 kb, u32 j) {
  u32 w0, w1;
  tf2x32(ka, kb, 0u, j, w0, w1);
  return w0 ^ w1;
}

__device__ __forceinline__ float u01f(u32 bits) {
  union { u32 i; float f; } v;
  v.i = (bits >> 9) | 0x3F800000u;
  return v.f - 1.0f;
}

// XLA f32 ErfInv (Giles polynomial)
__device__ __forceinline__ float erfinv32(float x) {
  float w = -log1pf(-x * x);
  float p;
  if (w < 5.0f) {
    w -= 2.5f;
    p = 2.81022636e-08f;
    p = fmaf(p, w, 3.43273939e-07f);
    p = fmaf(p, w, -3.5233877e-06f);
    p = fmaf(p, w, -4.39150654e-06f);
    p = fmaf(p, w, 0.00021858087f);
    p = fmaf(p, w, -0.00125372503f);
    p = fmaf(p, w, -0.00417768164f);
    p = fmaf(p, w, 0.246640727f);
    p = fmaf(p, w, 1.50140941f);
  } else {
    w = sqrtf(w) - 3.0f;
    p = -0.000200214257f;
    p = fmaf(p, w, 0.000100950558f);
    p = fmaf(p, w, 0.00134934322f);
    p = fmaf(p, w, -0.00367342844f);
    p = fmaf(p, w, 0.00573950773f);
    p = fmaf(p, w, -0.0076224613f);
    p = fmaf(p, w, 0.00943887047f);
    p = fmaf(p, w, 1.00167406f);
    p = fmaf(p, w, 2.83297682f);
  }
  return p * x;
}

__device__ __forceinline__ float nrmf(u32 bits) {
  float val = fmaf(u01f(bits), 2.0f, -0.99999994f);
  return 1.41421356f * erfinv32(val);
}
__device__ __forceinline__ float gumf(u32 bits) {
  float u = fmaxf(u01f(bits), 1.17549435e-38f);
  return -logf(-logf(u));
}
__device__ __forceinline__ float siluf(float x) {
  return x / (1.0f + expf(-x));
}

// ---- 8k weight chunk: 8 float2 (2 cols), row-major (coalesced) ----
struct Bf2 { float2 r0, r1, r2, r3, r4, r5, r6, r7; };

// two bases (rows 0-3 / 4-7) so offsets fold into the 13-bit imm
template<int LD>
__device__ __forceinline__ void loadBf2(Bf2& B, const float* p, int kk) {
  const float* q = p + kk * LD;
  const float* q2 = q + 4 * LD;
  B.r0 = *(const float2*)(q);
  B.r1 = *(const float2*)(q + LD);
  B.r2 = *(const float2*)(q + 2 * LD);
  B.r3 = *(const float2*)(q + 3 * LD);
  B.r4 = *(const float2*)(q2);
  B.r5 = *(const float2*)(q2 + LD);
  B.r6 = *(const float2*)(q2 + 2 * LD);
  B.r7 = *(const float2*)(q2 + 3 * LD);
}

__device__ __forceinline__ void fmaBf2(float acc[4], const float4 a0, const float4 a1,
                                       const float4 b0, const float4 b1, const Bf2& B) {
  acc[0]=fmaf(a0.x,B.r0.x,acc[0]); acc[1]=fmaf(a0.x,B.r0.y,acc[1]);
  acc[2]=fmaf(b0.x,B.r0.x,acc[2]); acc[3]=fmaf(b0.x,B.r0.y,acc[3]);
  acc[0]=fmaf(a0.y,B.r1.x,acc[0]); acc[1]=fmaf(a0.y,B.r1.y,acc[1]);
  acc[2]=fmaf(b0.y,B.r1.x,acc[2]); acc[3]=fmaf(b0.y,B.r1.y,acc[3]);
  acc[0]=fmaf(a0.z,B.r2.x,acc[0]); acc[1]=fmaf(a0.z,B.r2.y,acc[1]);
  acc[2]=fmaf(b0.z,B.r2.x,acc[2]); acc[3]=fmaf(b0.z,B.r2.y,acc[3]);
  acc[0]=fmaf(a0.w,B.r3.x,acc[0]); acc[1]=fmaf(a0.w,B.r3.y,acc[1]);
  acc[2]=fmaf(b0.w,B.r3.x,acc[2]); acc[3]=fmaf(b0.w,B.r3.y,acc[3]);
  acc[0]=fmaf(a1.x,B.r4.x,acc[0]); acc[1]=fmaf(a1.x,B.r4.y,acc[1]);
  acc[2]=fmaf(b1.x,B.r4.x,acc[2]); acc[3]=fmaf(b1.x,B.r4.y,acc[3]);
  acc[0]=fmaf(a1.y,B.r5.x,acc[0]); acc[1]=fmaf(a1.y,B.r5.y,acc[1]);
  acc[2]=fmaf(b1.y,B.r5.x,acc[2]); acc[3]=fmaf(b1.y,B.r5.y,acc[3]);
  acc[0]=fmaf(a1.z,B.r6.x,acc[0]); acc[1]=fmaf(a1.z,B.r6.y,acc[1]);
  acc[2]=fmaf(b1.z,B.r6.x,acc[2]); acc[3]=fmaf(b1.z,B.r6.y,acc[3]);
  acc[0]=fmaf(a1.w,B.r7.x,acc[0]); acc[1]=fmaf(a1.w,B.r7.y,acc[1]);
  acc[2]=fmaf(b1.w,B.r7.x,acc[2]); acc[3]=fmaf(b1.w,B.r7.y,acc[3]);
}

// 2-row x 2-col GEMM with distance-1 ping-pong prefetch. K%16==0.
template<int LD, int K>
__device__ __forceinline__ void gemmf2(float acc[4], const float* wp,
                                       const float* aA, const float* aB) {
  constexpr int n = K / 8;   // even
  Bf2 Bp, Bq;
  float4 xA0, xA1, xB0, xB1, yA0, yA1, yB0, yB1;
  loadBf2<LD>(Bp, wp, 0);
  xA0 = *(const float4*)(aA);     xA1 = *(const float4*)(aA + 4);
  xB0 = *(const float4*)(aB);     xB1 = *(const float4*)(aB + 4);
  #pragma unroll 2
  for (int j = 0; j < n; j += 2) {
    const int k1 = (j + 1) * 8;
    loadBf2<LD>(Bq, wp, k1);
    yA0 = *(const float4*)(aA + k1); yA1 = *(const float4*)(aA + k1 + 4);
    yB0 = *(const float4*)(aB + k1); yB1 = *(const float4*)(aB + k1 + 4);
    fmaBf2(acc, xA0, xA1, xB0, xB1, Bp);
    const int k2 = (j + 2 < n) ? (j + 2) * 8 : 0;   // last: dead in-bounds prefetch
    loadBf2<LD>(Bp, wp, k2);
    xA0 = *(const float4*)(aA + k2); xA1 = *(const float4*)(aA + k2 + 4);
    xB0 = *(const float4*)(aB + k2); xB1 = *(const float4*)(aB + k2 + 4);
    fmaBf2(acc, yA0, yA1, yB0, yB1, Bq);
  }
}

// ---- precompute: Ct[t][k][c] and step scalars into ws ----
__global__ void precompute_ct(
    const float* __restrict__ t_embed,
    const float* __restrict__ tm_w1, const float* __restrict__ tm_b1,
    const float* __restrict__ tm_w2, const float* __restrict__ tm_b2,
    const float* __restrict__ tr_w1, const float* __restrict__ tr_b1,
    float* __restrict__ ws)
{
  const int t = blockIdx.x + 1;
  const int c = threadIdx.x;
  __shared__ float tmpre[HID];
  __shared__ float tmv[HID];
  const float tau = (float)t / 50.0f;

  tmpre[c] = siluf(fmaf(tau, tm_w1[c], tm_b1[c]));
  __syncthreads();
  {
    float acc = tm_b2[c];
    for (int i = 0; i < HID; i++)
      acc = fmaf(tmpre[i], tm_w2[i * HID + c], acc);
    tmv[c] = acc;
  }
  __syncthreads();
  float D = 0.f;
  for (int i = 0; i < HID; i++)
    D = fmaf(tmv[i], tr_w1[(544 + i) * HID + c], D);
  float ce0 = tr_b1[c], ce1 = tr_b1[c];
  for (int i = 0; i < HID; i++) {
    ce0 = fmaf(t_embed[i], tr_w1[(288 + i) * HID + c], ce0);
    ce1 = fmaf(t_embed[HID + i], tr_w1[(288 + i) * HID + c], ce1);
  }
  ws[t * 512 + c] = ce0 + D;
  ws[t * 512 + 256 + c] = ce1 + D;

  if (c == 0) {
    const double lt = 6.214608098422191;  // ln 500
    float sig_t = (float)(0.002 * exp(((double)t / 50.0) * lt));
    float sig_p = (float)(0.002 * exp(((double)(t - 1) / 50.0) * lt));
    float stepf = sig_t * sig_t - sig_p * sig_p;
    ws[STEP_OFF + 2 * t] = stepf;
    ws[STEP_OFF + 2 * t + 1] = sqrtf(stepf);
  }
}

// ---- main sampler ----
__global__ __launch_bounds__(NTHR, 1) void sampler_k(
    const float* __restrict__ xy0, const int* __restrict__ t0,
    const float* __restrict__ tr_w1,
    const float* __restrict__ tr_w2, const float* __restrict__ tr_b2,
    const float* __restrict__ sh_w, const float* __restrict__ sh_b,
    const float* __restrict__ ch_w, const float* __restrict__ ch_b,
    const float* __restrict__ ws,
    float* __restrict__ out)
{
  __shared__ float xy_s[16][XYP];
  __shared__ float h1_s[16][HP];
  __shared__ float h2_s[16][HP];
  __shared__ float ct_s[2][HID];
  __shared__ int tcur_s[16];

  const int tid = threadIdx.x;
  const int lane = tid & 63;
  const int w = tid >> 6;                      // 16 waves; cols [16w, 16w+16)
  const int row0g = blockIdx.x * 16;

  const int r0 = lane >> 3;                    // rows r0, r0+8
  const int r1 = r0 + 8;
  const int cg = w * 16 + (lane & 7) * 2;      // 2 output cols
  const int rE = lane >> 2;                    // G3 extra (waves 0-7)
  const int cE = 256 + (w & 7) * 4 + (lane & 3);

  const float* w1b = tr_w1 + cg;
  const float* w2b = tr_w2 + cg;
  const float* swb = sh_w + cg;
  const float* epb = sh_w + cE;

  // ---- prologue ----
  for (int idx = tid; idx < 16 * (DXY / 4); idx += NTHR) {
    int r = idx / (DXY / 4);
    int q = idx - r * (DXY / 4);
    *(float4*)&xy_s[r][q * 4] = *(const float4*)(xy0 + (row0g + r) * DXY + q * 4);
  }
  if (tid < 16) tcur_s[tid] = t0[row0g + tid];
  if (tid < 512) ((float*)ct_s)[tid] = ws[49 * 512 + tid];

  float chw0[4], chw1[4];                      // logits: cols lane*4..+3
  #pragma unroll
  for (int j = 0; j < 4; j++) {
    chw0[j] = ch_w[(lane * 4 + j) * 2 + 0];
    chw1[j] = ch_w[(lane * 4 + j) * 2 + 1];
  }
  const float2 b2r = *(const float2*)(tr_b2 + cg);
  const float cb0 = ch_b[0], cb1 = ch_b[1];
  const float2 sbm = *(const float2*)(sh_b + cg);
  const float sbE = sh_b[cE];
  __syncthreads();

  #pragma unroll 1
  for (int t_idx = 49; t_idx >= 1; --t_idx) {
    const float stepf = ws[STEP_OFF + 2 * t_idx];
    const float sstep = ws[STEP_OFF + 2 * t_idx + 1];

    u32 f0, f1, k1a, k1b, k2a, k2b;
    tf2x32(0u, 42u, 0u, (u32)t_idx, f0, f1);
    tf2x32(f0, f1, 0u, 0u, k1a, k1b);
    tf2x32(f0, f1, 0u, 1u, k2a, k2b);

    // ---- G1: h1 = silu(xy @ W1[0:288] + Ct[t]) ----
    {
      const int tc0 = tcur_s[r0], tc1 = tcur_s[r1];
      float acc[4] = {0.f, 0.f, 0.f, 0.f};
      gemmf2<HID, 288>(acc, w1b, &xy_s[r0][0], &xy_s[r1][0]);
      const float2 ctA = *(const float2*)&ct_s[tc0][cg];
      const float2 ctB = *(const float2*)&ct_s[tc1][cg];
      float2 oA, oB;
      oA.x = siluf(acc[0] + ctA.x); oA.y = siluf(acc[1] + ctA.y);
      oB.x = siluf(acc[2] + ctB.x); oB.y = siluf(acc[3] + ctB.y);
      *(float2*)&h1_s[r0][cg] = oA;
      *(float2*)&h1_s[r1][cg] = oB;
    }
    __syncthreads();   // h1 ready

    // ---- G2: h2 = silu(h1 @ W2 + b2) ----
    {
      float acc[4] = {0.f, 0.f, 0.f, 0.f};
      gemmf2<HID, 256>(acc, w2b, &h1_s[r0][0], &h1_s[r1][0]);
      float2 oA, oB;
      oA.x = siluf(acc[0] + b2r.x); oA.y = siluf(acc[1] + b2r.y);
      oB.x = siluf(acc[2] + b2r.x); oB.y = siluf(acc[3] + b2r.y);
      *(float2*)&h2_s[r0][cg] = oA;
      *(float2*)&h2_s[r1][cg] = oB;
    }
    __syncthreads();   // h2 ready

    // ---- logits + categorical: wave w -> row w ----
    {
      float4 hL = *(const float4*)&h2_s[w][lane * 4];
      float p0 = hL.x * chw0[0] + hL.y * chw0[1] + hL.z * chw0[2] + hL.w * chw0[3];
      float p1 = hL.x * chw1[0] + hL.y * chw1[1] + hL.z * chw1[2] + hL.w * chw1[3];
      #pragma unroll
      for (int off = 32; off > 0; off >>= 1) {
        p0 += __shfl_xor(p0, off);
        p1 += __shfl_xor(p1, off);
      }
      float g = gumf(pbits(k2a, k2b, (u32)(row0g + w) * 2u + (u32)(lane & 1)));
      float g0 = __shfl(g, 0), g1 = __shfl(g, 1);
      if (lane == 0)
        tcur_s[w] = (p1 + cb1 + g1 > p0 + cb0 + g0) ? 1 : 0;
    }

    // ---- G3 main: score cols 0..255; xy += step*score + sqrt(step)*noise ----
    {
      float acc[4] = {0.f, 0.f, 0.f, 0.f};
      gemmf2<DXY, 256>(acc, swb, &h2_s[r0][0], &h2_s[r1][0]);
      const u32 jA = (u32)(row0g + r0) * 288u + (u32)cg;
      const u32 jB = (u32)(row0g + r1) * 288u + (u32)cg;
      float2 xA = *(const float2*)&xy_s[r0][cg];
      float2 xB = *(const float2*)&xy_s[r1][cg];
      xA.x = fmaf(sstep, nrmf(pbits(k1a, k1b, jA + 0u)), fmaf(stepf, acc[0] + sbm.x, xA.x));
      xA.y = fmaf(sstep, nrmf(pbits(k1a, k1b, jA + 1u)), fmaf(stepf, acc[1] + sbm.y, xA.y));
      xB.x = fmaf(sstep, nrmf(pbits(k1a, k1b, jB + 0u)), fmaf(stepf, acc[2] + sbm.x, xB.x));
      xB.y = fmaf(sstep, nrmf(pbits(k1a, k1b, jB + 1u)), fmaf(stepf, acc[3] + sbm.y, xB.y));
      *(float2*)&xy_s[r0][cg] = xA;
      *(float2*)&xy_s[r1][cg] = xB;
    }

    // ---- G3 extra: cols 256..287 (waves 0-7: 4 cols x 16 rows, 1/lane) ----
    if (w < 8) {
      float sE0 = 0.f, sE1 = 0.f;
      #pragma unroll 4
      for (int k = 0; k < 256; k += 8) {
        float4 h0  = *(const float4*)&h2_s[rE][k];
        float4 h1v = *(const float4*)&h2_s[rE][k + 4];
        const float* bp2 = epb + k * DXY;
        sE0 = fmaf(h0.w, bp2[3 * DXY], fmaf(h0.z, bp2[2 * DXY], fmaf(h0.y, bp2[DXY], fmaf(h0.x, bp2[0], sE0))));
        sE1 = fmaf(h1v.w, bp2[7 * DXY], fmaf(h1v.z, bp2[6 * DXY], fmaf(h1v.y, bp2[5 * DXY], fmaf(h1v.x, bp2[4 * DXY], sE1))));
      }
      float sE = sE0 + sE1;
      u32 jE = (u32)(row0g + rE) * 288u + (u32)cE;
      float nE = nrmf(pbits(k1a, k1b, jE));
      xy_s[rE][cE] = fmaf(sstep, nE, fmaf(stepf, sE + sbE, xy_s[rE][cE]));
    }

    // ---- stage Ct for next step ----
    if (t_idx > 1 && tid < 512) ((float*)ct_s)[tid] = ws[(t_idx - 1) * 512 + tid];
    __syncthreads();   // xy/tcur/ct ready for next G1
  }

  // ---- final store: x (4096x256), y (4096x32), t (4096) ----
  {
    int r = tid >> 6;
    int c4 = (tid & 63) * 4;
    *(float4*)(out + (row0g + r) * 256 + c4) = *(const float4*)&xy_s[r][c4];
  }
  if (tid < 16 * 8) {
    int r = tid >> 3;
    int c4 = (tid & 7) * 4;
    *(float4*)(out + OUT_Y_OFF + (row0g + r) * 32 + c4) = *(const float4*)&xy_s[r][256 + c4];
  }
  if (tid < 16) out[OUT_T_OFF + row0g + tid] = (float)tcur_s[tid];
}

extern "C" void kernel_launch(void* const* d_in, const int* in_sizes, int n_in,
                              void* d_out, int out_size, void* d_ws, size_t ws_size,
                              hipStream_t stream) {
  (void)in_sizes; (void)n_in; (void)ws_size; (void)out_size;
  const float* xy0     = (const float*)d_in[0];
  const int*   t0      = (const int*)d_in[1];
  const float* t_embed = (const float*)d_in[2];
  const float* tm_w1   = (const float*)d_in[3];
  const float* tm_b1   = (const float*)d_in[4];
  const float* tm_w2   = (const float*)d_in[5];
  const float* tm_b2   = (const float*)d_in[6];
  const float* tr_w1   = (const float*)d_in[7];
  const float* tr_b1   = (const float*)d_in[8];
  const float* tr_w2   = (const float*)d_in[9];
  const float* tr_b2   = (const float*)d_in[10];
  const float* sh_w    = (const float*)d_in[11];
  const float* sh_b    = (const float*)d_in[12];
  const float* ch_w    = (const float*)d_in[13];
  const float* ch_b    = (const float*)d_in[14];
  float* ws  = (float*)d_ws;
  float* out = (float*)d_out;

  precompute_ct<<<49, 256, 0, stream>>>(t_embed, tm_w1, tm_b1, tm_w2, tm_b2,
                                        tr_w1, tr_b1, ws);
  sampler_k<<<256, NTHR, 0, stream>>>(xy0, t0, tr_w1, tr_w2, tr_b2,
                                      sh_w, sh_b, ch_w, ch_b, ws, out);
}

// Round 10
// 2809.234 us; speedup vs baseline: 3.3099x; 1.6909x over previous
//
#include <hip/hip_runtime.h>
#include <math.h>

// Diffusion sampler: 49 sequential steps, rows independent.
// Round 10 = R6 structure + R7 ping-pong registers + coalesced NT weights.
// 256 blocks x 512 threads ((512,2): measured 128-VGPR budget, no spill in R7).
// 16 rows/block; wave w owns cols [32w,32w+32); lane: 2 rows x 4 cols.
// Weights stream once per CU per step, row-major float4 loads (coalesced).
// Distance-1 ping-pong register prefetch in all GEMM loops.
// All f32. PRNG: JAX threefry2x32, partitionable mode.

#define DXY 288
#define HID 256
#define NTHR 512
#define XYP 296                 // xy_s stride: rows 8 banks apart -> 2-way max (free)
#define HP  264                 // h_s stride
#define OUT_Y_OFF 1048576
#define OUT_T_OFF 1179648
#define STEP_OFF 25600          // ws: ct at t*512; [stepf,sstep] at STEP_OFF+2t

typedef unsigned int u32;

__device__ __forceinline__ void tf2x32(u32 k0, u32 k1, u32 x0, u32 x1, u32& o0, u32& o1) {
  u32 ks2 = k0 ^ k1 ^ 0x1BD11BDAu;
#define TFR(r) { x0 += x1; x1 = (x1 << (r)) | (x1 >> (32 - (r))); x1 ^= x0; }
  x0 += k0; x1 += k1;
  TFR(13) TFR(15) TFR(26) TFR(6)
  x0 += k1;  x1 += ks2 + 1u;
  TFR(17) TFR(29) TFR(16) TFR(24)
  x0 += ks2; x1 += k0 + 2u;
  TFR(13) TFR(15) TFR(26) TFR(6)
  x0 += k0;  x1 += k1 + 3u;
  TFR(17) TFR(29) TFR(16) TFR(24)
  x0 += k1;  x1 += ks2 + 4u;
  TFR(13) TFR(15) TFR(26) TFR(6)
  x0 += ks2; x1 += k0 + 5u;
#undef TFR
  o0 = x0; o1 = x1;
}

__device__ __forceinline__ u32 pbits(u32 ka, u32 kb, u32 j) {
  u32 w0, w1;
  tf2x32(ka, kb, 0u, j, w0, w1);
  return w0 ^ w1;
}

__device__ __forceinline__ float u01f(u32 bits) {
  union { u32 i; float f; } v;
  v.i = (bits >> 9) | 0x3F800000u;
  return v.f - 1.0f;
}

// XLA f32 ErfInv (Giles polynomial)
__device__ __forceinline__ float erfinv32(float x) {
  float w = -log1pf(-x * x);
  float p;
  if (w < 5.0f) {
    w -= 2.5f;
    p = 2.81022636e-08f;
    p = fmaf(p, w, 3.43273939e-07f);
    p = fmaf(p, w, -3.5233877e-06f);
    p = fmaf(p, w, -4.39150654e-06f);
    p = fmaf(p, w, 0.00021858087f);
    p = fmaf(p, w, -0.00125372503f);
    p = fmaf(p, w, -0.00417768164f);
    p = fmaf(p, w, 0.246640727f);
    p = fmaf(p, w, 1.50140941f);
  } else {
    w = sqrtf(w) - 3.0f;
    p = -0.000200214257f;
    p = fmaf(p, w, 0.000100950558f);
    p = fmaf(p, w, 0.00134934322f);
    p = fmaf(p, w, -0.00367342844f);
    p = fmaf(p, w, 0.00573950773f);
    p = fmaf(p, w, -0.0076224613f);
    p = fmaf(p, w, 0.00943887047f);
    p = fmaf(p, w, 1.00167406f);
    p = fmaf(p, w, 2.83297682f);
  }
  return p * x;
}

__device__ __forceinline__ float nrmf(u32 bits) {
  float val = fmaf(u01f(bits), 2.0f, -0.99999994f);
  return 1.41421356f * erfinv32(val);
}
__device__ __forceinline__ float gumf(u32 bits) {
  float u = fmaxf(u01f(bits), 1.17549435e-38f);
  return -logf(-logf(u));
}
__device__ __forceinline__ float siluf(float x) {
  return x / (1.0f + expf(-x));
}

// ---- 8k weight chunk: 8 rows x 4 cols, row-major float4 (coalesced) ----
struct B8 { float4 a0, a1, a2, a3, b0, b1, b2, b3; };

// two bases (rows kk..kk+3 / kk+4..kk+7) so i*LD*4 <= 3KB folds into 13-bit imm
template<int LD>
__device__ __forceinline__ void loadB8(B8& B, const float* p, int kk) {
  const float* q = p + kk * LD;
  const float* q2 = q + 4 * LD;
  B.a0 = *(const float4*)(q);
  B.a1 = *(const float4*)(q + LD);
  B.a2 = *(const float4*)(q + 2 * LD);
  B.a3 = *(const float4*)(q + 3 * LD);
  B.b0 = *(const float4*)(q2);
  B.b1 = *(const float4*)(q2 + LD);
  B.b2 = *(const float4*)(q2 + 2 * LD);
  B.b3 = *(const float4*)(q2 + 3 * LD);
}

// acc[c] += sum over 8 k of x[k] * B[k][c]  (k order preserved: a0..a3,b0..b3)
__device__ __forceinline__ void fma8x4(float acc[4], const float4 x0, const float4 x1, const B8& B) {
  acc[0]=fmaf(x0.x,B.a0.x,acc[0]); acc[1]=fmaf(x0.x,B.a0.y,acc[1]); acc[2]=fmaf(x0.x,B.a0.z,acc[2]); acc[3]=fmaf(x0.x,B.a0.w,acc[3]);
  acc[0]=fmaf(x0.y,B.a1.x,acc[0]); acc[1]=fmaf(x0.y,B.a1.y,acc[1]); acc[2]=fmaf(x0.y,B.a1.z,acc[2]); acc[3]=fmaf(x0.y,B.a1.w,acc[3]);
  acc[0]=fmaf(x0.z,B.a2.x,acc[0]); acc[1]=fmaf(x0.z,B.a2.y,acc[1]); acc[2]=fmaf(x0.z,B.a2.z,acc[2]); acc[3]=fmaf(x0.z,B.a2.w,acc[3]);
  acc[0]=fmaf(x0.w,B.a3.x,acc[0]); acc[1]=fmaf(x0.w,B.a3.y,acc[1]); acc[2]=fmaf(x0.w,B.a3.z,acc[2]); acc[3]=fmaf(x0.w,B.a3.w,acc[3]);
  acc[0]=fmaf(x1.x,B.b0.x,acc[0]); acc[1]=fmaf(x1.x,B.b0.y,acc[1]); acc[2]=fmaf(x1.x,B.b0.z,acc[2]); acc[3]=fmaf(x1.x,B.b0.w,acc[3]);
  acc[0]=fmaf(x1.y,B.b1.x,acc[0]); acc[1]=fmaf(x1.y,B.b1.y,acc[1]); acc[2]=fmaf(x1.y,B.b1.z,acc[2]); acc[3]=fmaf(x1.y,B.b1.w,acc[3]);
  acc[0]=fmaf(x1.z,B.b2.x,acc[0]); acc[1]=fmaf(x1.z,B.b2.y,acc[1]); acc[2]=fmaf(x1.z,B.b2.z,acc[2]); acc[3]=fmaf(x1.z,B.b2.w,acc[3]);
  acc[0]=fmaf(x1.w,B.b3.x,acc[0]); acc[1]=fmaf(x1.w,B.b3.y,acc[1]); acc[2]=fmaf(x1.w,B.b3.z,acc[2]); acc[3]=fmaf(x1.w,B.b3.w,acc[3]);
}

// 2-row x 4-col GEMM tile with distance-1 ping-pong prefetch. K%16==0.
// A rows have >=8 floats of pad past K (XYP/HP) for the dead epilogue reads.
template<int LD, int K>
__device__ __forceinline__ void gemm2(float accA[4], float accB[4],
                                      const float* wp, const float* aA, const float* aB) {
  B8 Bp, Bq;
  float4 xA0 = *(const float4*)(aA),  xA1 = *(const float4*)(aA + 4);
  float4 xB0 = *(const float4*)(aB),  xB1 = *(const float4*)(aB + 4);
  loadB8<LD>(Bp, wp, 0);
  #pragma unroll 2
  for (int j = 0; j < K / 16; ++j) {
    const int k1 = j * 16 + 8;
    const int k2t = j * 16 + 16;
    const int k2 = (k2t < K) ? k2t : 0;          // final prefetch: dead, in-bounds
    loadB8<LD>(Bq, wp, k1);
    float4 yA0 = *(const float4*)(aA + k1), yA1 = *(const float4*)(aA + k1 + 4);
    float4 yB0 = *(const float4*)(aB + k1), yB1 = *(const float4*)(aB + k1 + 4);
    fma8x4(accA, xA0, xA1, Bp);
    fma8x4(accB, xB0, xB1, Bp);
    loadB8<LD>(Bp, wp, k2);
    xA0 = *(const float4*)(aA + k2); xA1 = *(const float4*)(aA + k2 + 4);
    xB0 = *(const float4*)(aB + k2); xB1 = *(const float4*)(aB + k2 + 4);
    fma8x4(accA, yA0, yA1, Bq);
    fma8x4(accB, yB0, yB1, Bq);
  }
}

// ---- precompute: Ct[t][k][c] and step scalars into ws ----
__global__ void precompute_ct(
    const float* __restrict__ t_embed,
    const float* __restrict__ tm_w1, const float* __restrict__ tm_b1,
    const float* __restrict__ tm_w2, const float* __restrict__ tm_b2,
    const float* __restrict__ tr_w1, const float* __restrict__ tr_b1,
    float* __restrict__ ws)
{
  const int t = blockIdx.x + 1;
  const int c = threadIdx.x;
  __shared__ float tmpre[HID];
  __shared__ float tmv[HID];
  const float tau = (float)t / 50.0f;

  tmpre[c] = siluf(fmaf(tau, tm_w1[c], tm_b1[c]));
  __syncthreads();
  {
    float acc = tm_b2[c];
    for (int i = 0; i < HID; i++)
      acc = fmaf(tmpre[i], tm_w2[i * HID + c], acc);
    tmv[c] = acc;
  }
  __syncthreads();
  float D = 0.f;
  for (int i = 0; i < HID; i++)
    D = fmaf(tmv[i], tr_w1[(544 + i) * HID + c], D);
  float ce0 = tr_b1[c], ce1 = tr_b1[c];
  for (int i = 0; i < HID; i++) {
    ce0 = fmaf(t_embed[i], tr_w1[(288 + i) * HID + c], ce0);
    ce1 = fmaf(t_embed[HID + i], tr_w1[(288 + i) * HID + c], ce1);
  }
  ws[t * 512 + c] = ce0 + D;
  ws[t * 512 + 256 + c] = ce1 + D;

  if (c == 0) {
    const double lt = 6.214608098422191;  // ln 500
    float sig_t = (float)(0.002 * exp(((double)t / 50.0) * lt));
    float sig_p = (float)(0.002 * exp(((double)(t - 1) / 50.0) * lt));
    float stepf = sig_t * sig_t - sig_p * sig_p;
    ws[STEP_OFF + 2 * t] = stepf;
    ws[STEP_OFF + 2 * t + 1] = sqrtf(stepf);
  }
}

// ---- main sampler: column-tiled waves, ping-pong prefetch, NT weights ----
__global__ __launch_bounds__(NTHR, 2) void sampler_k(
    const float* __restrict__ xy0, const int* __restrict__ t0,
    const float* __restrict__ tr_w1,
    const float* __restrict__ tr_w2, const float* __restrict__ tr_b2,
    const float* __restrict__ sh_w, const float* __restrict__ sh_b,
    const float* __restrict__ ch_w, const float* __restrict__ ch_b,
    const float* __restrict__ ws,
    float* __restrict__ out)
{
  __shared__ float xy_s[16][XYP];
  __shared__ float h1_s[16][HP];
  __shared__ float h2_s[16][HP];
  __shared__ float ct_s[2][HID];
  __shared__ int tcur_s[16];

  const int tid = threadIdx.x;
  const int lane = tid & 63;
  const int w = tid >> 6;                    // 8 waves; wave w: cols [32w, 32w+32)
  const int row0g = blockIdx.x * 16;

  const int r0 = lane >> 3;                  // rows r0, r0+8
  const int r1 = r0 + 8;
  const int cg = w * 32 + (lane & 7) * 4;    // 4 output cols
  const int rE = lane >> 2;                  // G3 extra: 16 rows x 4 cols/wave
  const int cE = 256 + w * 4 + (lane & 3);

  const float* w1b = tr_w1 + cg;
  const float* w2b = tr_w2 + cg;
  const float* swb = sh_w + cg;
  const float* epb = sh_w + cE;

  // ---- prologue ----
  for (int idx = tid; idx < 16 * (DXY / 4); idx += NTHR) {
    int r = idx / (DXY / 4);
    int q = idx - r * (DXY / 4);
    *(float4*)&xy_s[r][q * 4] = *(const float4*)(xy0 + (row0g + r) * DXY + q * 4);
  }
  if (tid < 16) tcur_s[tid] = t0[row0g + tid];
  ((float*)ct_s)[tid] = ws[49 * 512 + tid];

  float chw0[4], chw1[4];                    // logits: cols lane*4..+3
  #pragma unroll
  for (int j = 0; j < 4; j++) {
    chw0[j] = ch_w[(lane * 4 + j) * 2 + 0];
    chw1[j] = ch_w[(lane * 4 + j) * 2 + 1];
  }
  const float4 b2r = *(const float4*)(tr_b2 + cg);
  const float cb0 = ch_b[0], cb1 = ch_b[1];
  const float4 sbm = *(const float4*)(sh_b + cg);
  const float sbE = sh_b[cE];
  __syncthreads();

  #pragma unroll 1
  for (int t_idx = 49; t_idx >= 1; --t_idx) {
    const float stepf = ws[STEP_OFF + 2 * t_idx];
    const float sstep = ws[STEP_OFF + 2 * t_idx + 1];

    u32 f0, f1, k1a, k1b, k2a, k2b;
    tf2x32(0u, 42u, 0u, (u32)t_idx, f0, f1);
    tf2x32(f0, f1, 0u, 0u, k1a, k1b);
    tf2x32(f0, f1, 0u, 1u, k2a, k2b);

    // ---- G1: h1 = silu(xy @ W1[0:288] + Ct[t]) ----
    {
      const int tc0 = tcur_s[r0], tc1 = tcur_s[r1];
      float accA[4] = {0.f, 0.f, 0.f, 0.f};
      float accB[4] = {0.f, 0.f, 0.f, 0.f};
      gemm2<HID, 288>(accA, accB, w1b, &xy_s[r0][0], &xy_s[r1][0]);
      const float4 ctA = *(const float4*)&ct_s[tc0][cg];
      const float4 ctB = *(const float4*)&ct_s[tc1][cg];
      float4 oA, oB;
      oA.x = siluf(accA[0] + ctA.x); oA.y = siluf(accA[1] + ctA.y);
      oA.z = siluf(accA[2] + ctA.z); oA.w = siluf(accA[3] + ctA.w);
      oB.x = siluf(accB[0] + ctB.x); oB.y = siluf(accB[1] + ctB.y);
      oB.z = siluf(accB[2] + ctB.z); oB.w = siluf(accB[3] + ctB.w);
      *(float4*)&h1_s[r0][cg] = oA;
      *(float4*)&h1_s[r1][cg] = oB;
    }
    __syncthreads();   // h1 ready

    // ---- G2: h2 = silu(h1 @ W2 + b2) ----
    {
      float accA[4] = {0.f, 0.f, 0.f, 0.f};
      float accB[4] = {0.f, 0.f, 0.f, 0.f};
      gemm2<HID, 256>(accA, accB, w2b, &h1_s[r0][0], &h1_s[r1][0]);
      float4 oA, oB;
      oA.x = siluf(accA[0] + b2r.x); oA.y = siluf(accA[1] + b2r.y);
      oA.z = siluf(accA[2] + b2r.z); oA.w = siluf(accA[3] + b2r.w);
      oB.x = siluf(accB[0] + b2r.x); oB.y = siluf(accB[1] + b2r.y);
      oB.z = siluf(accB[2] + b2r.z); oB.w = siluf(accB[3] + b2r.w);
      *(float4*)&h2_s[r0][cg] = oA;
      *(float4*)&h2_s[r1][cg] = oB;
    }
    __syncthreads();   // h2 ready

    // ---- logits + categorical for rows {2w, 2w+1} ----
    {
      float4 hL0 = *(const float4*)&h2_s[2 * w][lane * 4];
      float4 hL1 = *(const float4*)&h2_s[2 * w + 1][lane * 4];
      float pA0 = hL0.x * chw0[0] + hL0.y * chw0[1] + hL0.z * chw0[2] + hL0.w * chw0[3];
      float pA1 = hL0.x * chw1[0] + hL0.y * chw1[1] + hL0.z * chw1[2] + hL0.w * chw1[3];
      float pB0 = hL1.x * chw0[0] + hL1.y * chw0[1] + hL1.z * chw0[2] + hL1.w * chw0[3];
      float pB1 = hL1.x * chw1[0] + hL1.y * chw1[1] + hL1.z * chw1[2] + hL1.w * chw1[3];
      #pragma unroll
      for (int off = 32; off > 0; off >>= 1) {
        pA0 += __shfl_xor(pA0, off);
        pA1 += __shfl_xor(pA1, off);
        pB0 += __shfl_xor(pB0, off);
        pB1 += __shfl_xor(pB1, off);
      }
      u32 grow = (u32)(row0g + 2 * w + ((lane >> 1) & 1));
      float g = gumf(pbits(k2a, k2b, grow * 2u + (u32)(lane & 1)));
      float g0 = __shfl(g, 0), g1 = __shfl(g, 1);
      float g2 = __shfl(g, 2), g3 = __shfl(g, 3);
      if (lane == 0) {
        tcur_s[2 * w]     = (pA1 + cb1 + g1 > pA0 + cb0 + g0) ? 1 : 0;
        tcur_s[2 * w + 1] = (pB1 + cb1 + g3 > pB0 + cb0 + g2) ? 1 : 0;
      }
    }

    // ---- G3 main: score cols 0..255; xy += step*score + sqrt(step)*noise ----
    {
      float accA[4] = {0.f, 0.f, 0.f, 0.f};
      float accB[4] = {0.f, 0.f, 0.f, 0.f};
      gemm2<DXY, 256>(accA, accB, swb, &h2_s[r0][0], &h2_s[r1][0]);
      const u32 jA = (u32)(row0g + r0) * 288u + (u32)cg;
      const u32 jB = (u32)(row0g + r1) * 288u + (u32)cg;
      float4 xA = *(const float4*)&xy_s[r0][cg];
      float4 xB = *(const float4*)&xy_s[r1][cg];
      xA.x = fmaf(sstep, nrmf(pbits(k1a, k1b, jA + 0u)), fmaf(stepf, accA[0] + sbm.x, xA.x));
      xA.y = fmaf(sstep, nrmf(pbits(k1a, k1b, jA + 1u)), fmaf(stepf, accA[1] + sbm.y, xA.y));
      xA.z = fmaf(sstep, nrmf(pbits(k1a, k1b, jA + 2u)), fmaf(stepf, accA[2] + sbm.z, xA.z));
      xA.w = fmaf(sstep, nrmf(pbits(k1a, k1b, jA + 3u)), fmaf(stepf, accA[3] + sbm.w, xA.w));
      xB.x = fmaf(sstep, nrmf(pbits(k1a, k1b, jB + 0u)), fmaf(stepf, accB[0] + sbm.x, xB.x));
      xB.y = fmaf(sstep, nrmf(pbits(k1a, k1b, jB + 1u)), fmaf(stepf, accB[1] + sbm.y, xB.y));
      xB.z = fmaf(sstep, nrmf(pbits(k1a, k1b, jB + 2u)), fmaf(stepf, accB[2] + sbm.z, xB.z));
      xB.w = fmaf(sstep, nrmf(pbits(k1a, k1b, jB + 3u)), fmaf(stepf, accB[3] + sbm.w, xB.w));
      *(float4*)&xy_s[r0][cg] = xA;
      *(float4*)&xy_s[r1][cg] = xB;
    }

    // ---- G3 extra: cols 256..287 (wave w: 4 cols x 16 rows, 1/lane) ----
    {
      float sE0 = 0.f, sE1 = 0.f;
      #pragma unroll 4
      for (int k = 0; k < 256; k += 8) {
        float4 h0  = *(const float4*)&h2_s[rE][k];
        float4 h1v = *(const float4*)&h2_s[rE][k + 4];
        const float* bp2 = epb + k * DXY;
        sE0 = fmaf(h0.w, bp2[3 * DXY], fmaf(h0.z, bp2[2 * DXY], fmaf(h0.y, bp2[DXY], fmaf(h0.x, bp2[0], sE0))));
        sE1 = fmaf(h1v.w, bp2[7 * DXY], fmaf(h1v.z, bp2[6 * DXY], fmaf(h1v.y, bp2[5 * DXY], fmaf(h1v.x, bp2[4 * DXY], sE1))));
      }
      float sE = sE0 + sE1;
      u32 jE = (u32)(row0g + rE) * 288u + (u32)cE;
      float nE = nrmf(pbits(k1a, k1b, jE));
      xy_s[rE][cE] = fmaf(sstep, nE, fmaf(stepf, sE + sbE, xy_s[rE][cE]));
    }

    // ---- stage Ct for next step ----
    if (t_idx > 1) ((float*)ct_s)[tid] = ws[(t_idx - 1) * 512 + tid];
    __syncthreads();   // xy/tcur/ct ready for next G1
  }

  // ---- final store: x (4096x256), y (4096x32), t (4096) ----
  for (int idx = tid; idx < 16 * 64; idx += NTHR) {
    int r = idx >> 6;
    int c4 = (idx & 63) * 4;
    *(float4*)(out + (row0g + r) * 256 + c4) = *(const float4*)&xy_s[r][c4];
  }
  for (int idx = tid; idx < 16 * 8; idx += NTHR) {
    int r = idx >> 3;
    int c4 = (idx & 7) * 4;
    *(float4*)(out + OUT_Y_OFF + (row0g + r) * 32 + c4) = *(const float4*)&xy_s[r][256 + c4];
  }
  if (tid < 16) out[OUT_T_OFF + row0g + tid] = (float)tcur_s[tid];
}

extern "C" void kernel_launch(void* const* d_in, const int* in_sizes, int n_in,
                              void* d_out, int out_size, void* d_ws, size_t ws_size,
                              hipStream_t stream) {
  (void)in_sizes; (void)n_in; (void)ws_size; (void)out_size;
  const float* xy0     = (const float*)d_in[0];
  const int*   t0      = (const int*)d_in[1];
  const float* t_embed = (const float*)d_in[2];
  const float* tm_w1   = (const float*)d_in[3];
  const float* tm_b1   = (const float*)d_in[4];
  const float* tm_w2   = (const float*)d_in[5];
  const float* tm_b2   = (const float*)d_in[6];
  const float* tr_w1   = (const float*)d_in[7];
  const float* tr_b1   = (const float*)d_in[8];
  const float* tr_w2   = (const float*)d_in[9];
  const float* tr_b2   = (const float*)d_in[10];
  const float* sh_w    = (const float*)d_in[11];
  const float* sh_b    = (const float*)d_in[12];
  const float* ch_w    = (const float*)d_in[13];
  const float* ch_b    = (const float*)d_in[14];
  float* ws  = (float*)d_ws;
  float* out = (float*)d_out;

  precompute_ct<<<49, 256, 0, stream>>>(t_embed, tm_w1, tm_b1, tm_w2, tm_b2,
                                        tr_w1, tr_b1, ws);
  sampler_k<<<256, NTHR, 0, stream>>>(xy0, t0, tr_w1, tr_w2, tr_b2,
                                      sh_w, sh_b, ch_w, ch_b, ws, out);
}